// Round 1
// baseline (630.457 us; speedup 1.0000x reference)
//
#include <hip/hip_runtime.h>
#include <stdint.h>

#define NB 32
#define SL 1024
#define HD 512
#define NS (NB * SL)   // 32768

typedef __attribute__((ext_vector_type(8))) short short8;   // 8 x bf16
typedef __attribute__((ext_vector_type(4))) float f32x4;

__device__ __forceinline__ unsigned short f2bf(float f) {
    union { float f; uint32_t u; } c; c.f = f;
    uint32_t u = c.u;
    return (unsigned short)((u + 0x7FFFu + ((u >> 16) & 1u)) >> 16);
}

__device__ __forceinline__ void gl_lds16(const void* g, void* l) {
    __builtin_amdgcn_global_load_lds(
        (const __attribute__((address_space(1))) uint32_t*)g,
        (__attribute__((address_space(3))) uint32_t*)l, 16, 0, 0);
}

// ---------------- utility kernels ----------------
__global__ void k_zero(float* p, int n) {
    int i = threadIdx.x;
    if (i < n) p[i] = 0.f;
}

__global__ void k_cvt(const float* __restrict__ in, unsigned short* __restrict__ out, int n8) {
    int i = blockIdx.x * blockDim.x + threadIdx.x;
    int stride = gridDim.x * blockDim.x;
    for (; i < n8; i += stride) {
        const float4* p = (const float4*)in + (size_t)i * 2;
        float4 a = p[0], b = p[1];
        short8 v;
        v[0] = (short)f2bf(a.x); v[1] = (short)f2bf(a.y);
        v[2] = (short)f2bf(a.z); v[3] = (short)f2bf(a.w);
        v[4] = (short)f2bf(b.x); v[5] = (short)f2bf(b.y);
        v[6] = (short)f2bf(b.z); v[7] = (short)f2bf(b.w);
        *((short8*)out + i) = v;
    }
}

// ---------------- bf16 GEMM: C[M][N] = A[M][K] * B[N][K]^T + bias ----------------
// BIAS_M==0: bias indexed by n (col); BIAS_M==1: bias indexed by m (row).
template<int BIAS_M>
__global__ __launch_bounds__(256, 4)
void k_gemm_bt(const unsigned short* __restrict__ A,
               const unsigned short* __restrict__ Bm,
               const float* __restrict__ bias,
               unsigned short* __restrict__ C,
               int M, int N, int K) {
    __shared__ unsigned short As[128 * 64];   // [128 rows][64 k] XOR-swizzled in 16B chunks
    __shared__ unsigned short Bs[128 * 64];
    const int t = threadIdx.x;
    const int lane = t & 63, w = t >> 6;
    const int wr = w >> 1, wc = w & 1;        // 2x2 wave grid, 64x64 per wave
    const int g = lane >> 4, lr = lane & 15;
    const int m0 = blockIdx.y * 128, n0 = blockIdx.x * 128;

    f32x4 acc[4][4];
#pragma unroll
    for (int i = 0; i < 4; i++)
#pragma unroll
        for (int j = 0; j < 4; j++) acc[i][j] = (f32x4){0.f, 0.f, 0.f, 0.f};

    for (int kt = 0; kt < K; kt += 64) {
        // stage A and B: 1024 16B-chunks each; linear LDS dest, inverse-swizzled global src
#pragma unroll
        for (int i = 0; i < 4; i++) {
            int u = i * 256 + t;
            int row = u >> 3, c = u & 7;
            int sc = c ^ (row & 7);
            gl_lds16(A + (size_t)(m0 + row) * K + kt + sc * 8,
                     (char*)As + (size_t)(i * 256 + w * 64) * 16);
        }
#pragma unroll
        for (int i = 0; i < 4; i++) {
            int u = i * 256 + t;
            int row = u >> 3, c = u & 7;
            int sc = c ^ (row & 7);
            gl_lds16(Bm + (size_t)(n0 + row) * K + kt + sc * 8,
                     (char*)Bs + (size_t)(i * 256 + w * 64) * 16);
        }
        __syncthreads();
#pragma unroll
        for (int ks = 0; ks < 2; ks++) {
            short8 af[4], bf[4];
#pragma unroll
            for (int mf = 0; mf < 4; mf++) {
                int row = wr * 64 + mf * 16 + lr;
                int ch = (ks * 4 + g) ^ (row & 7);
                af[mf] = *(const short8*)((const char*)As + row * 128 + ch * 16);
            }
#pragma unroll
            for (int nf = 0; nf < 4; nf++) {
                int row = wc * 64 + nf * 16 + lr;
                int ch = (ks * 4 + g) ^ (row & 7);
                bf[nf] = *(const short8*)((const char*)Bs + row * 128 + ch * 16);
            }
#pragma unroll
            for (int mf = 0; mf < 4; mf++)
#pragma unroll
                for (int nf = 0; nf < 4; nf++)
                    acc[mf][nf] = __builtin_amdgcn_mfma_f32_16x16x32_bf16(
                        af[mf], bf[nf], acc[mf][nf], 0, 0, 0);
        }
        __syncthreads();
    }
#pragma unroll
    for (int mf = 0; mf < 4; mf++) {
#pragma unroll
        for (int nf = 0; nf < 4; nf++) {
            int col = n0 + wc * 64 + nf * 16 + lr;
            int row0 = m0 + wr * 64 + mf * 16 + g * 4;
#pragma unroll
            for (int r = 0; r < 4; r++) {
                float v = acc[mf][nf][r] + (BIAS_M ? bias[row0 + r] : bias[col]);
                C[(size_t)(row0 + r) * N + col] = f2bf(v);
            }
        }
    }
}

// ---------------- fused attention ----------------
// One block: batch b, 64 q-rows. 8 waves, 512 threads.
// K processed as 2 tiles of 512; exact online softmax; mask applied post-softmax.
// Qs/Ps XOR-swizzled per 16B chunk within each 1KB row.
__global__ __launch_bounds__(512, 2)
void k_flash(const unsigned short* __restrict__ Qb,   // [NS][HD] bf16
             const unsigned short* __restrict__ Kb,   // [NS][HD] bf16
             const unsigned short* __restrict__ Vt,   // [HD][NS] bf16
             const float* __restrict__ mask,          // [NB][SL][SL]
             float* __restrict__ out,                 // [NB][SL][HD]
             float* __restrict__ denom) {             // [NB]
    __shared__ unsigned short Qs[64 * 512];
    __shared__ unsigned short Ps[64 * 512];
    __shared__ float wred[8][64];
    __shared__ float wredA[8][64];
    __shared__ float tred[64];
    __shared__ float tredA[64];

    const int t = threadIdx.x;
    const int lane = t & 63, w = t >> 6;
    const int g = lane >> 4, lr = lane & 15;
    const int qt = blockIdx.x, b = blockIdx.y;
    const int q0 = qt * 64;

    // stage Q tile (64x512 bf16 = 64KB), inverse-swizzled source
    const unsigned short* Qg = Qb + (size_t)(b * SL + q0) * HD;
#pragma unroll
    for (int i = 0; i < 8; i++) {
        int u = i * 512 + t;
        int row = u >> 6, c = u & 63;
        int sc = c ^ (row & 7);
        gl_lds16(Qg + (size_t)row * HD + sc * 8,
                 (char*)Qs + (size_t)(i * 512 + w * 64) * 16);
    }

    float m_r[4][4], l_r[4][4], sA_r[4][4], alpha[4][4];
    f32x4 O[4][4];
#pragma unroll
    for (int i = 0; i < 4; i++)
#pragma unroll
        for (int j = 0; j < 4; j++) {
            m_r[i][j] = -1e30f; l_r[i][j] = 0.f; sA_r[i][j] = 0.f;
            O[i][j] = (f32x4){0.f, 0.f, 0.f, 0.f};
        }
    __syncthreads();

    const float iscale = 0.04419417382415922f;  // 1/sqrt(512)

    for (int kt = 0; kt < 2; kt++) {
        // ---- QK^T: P[q 64][k 64-per-wave], contraction over h=512 ----
        f32x4 P[4][4];
#pragma unroll
        for (int i = 0; i < 4; i++)
#pragma unroll
            for (int j = 0; j < 4; j++) P[i][j] = (f32x4){0.f, 0.f, 0.f, 0.f};

        const unsigned short* Kg = Kb + (size_t)(b * SL + kt * 512 + w * 64) * HD;
#pragma unroll 2
        for (int h = 0; h < HD; h += 32) {
            short8 qa[4], kb8[4];
            int chb = (h >> 3) + g;
#pragma unroll
            for (int mf = 0; mf < 4; mf++) {
                int row = mf * 16 + lr;
                qa[mf] = *(const short8*)((const char*)Qs + row * 1024 + ((chb ^ (row & 7)) << 4));
            }
#pragma unroll
            for (int nf = 0; nf < 4; nf++)
                kb8[nf] = *(const short8*)(Kg + (size_t)(nf * 16 + lr) * HD + h + g * 8);
#pragma unroll
            for (int mf = 0; mf < 4; mf++)
#pragma unroll
                for (int nf = 0; nf < 4; nf++)
                    P[mf][nf] = __builtin_amdgcn_mfma_f32_16x16x32_bf16(
                        qa[mf], kb8[nf], P[mf][nf], 0, 0, 0);
        }
#pragma unroll
        for (int mf = 0; mf < 4; mf++)
#pragma unroll
            for (int nf = 0; nf < 4; nf++) P[mf][nf] *= iscale;

        // ---- row max over this K-tile ----
        float pmax[4][4];
#pragma unroll
        for (int mf = 0; mf < 4; mf++)
#pragma unroll
            for (int r = 0; r < 4; r++) {
                float v = fmaxf(fmaxf(P[mf][0][r], P[mf][1][r]),
                                fmaxf(P[mf][2][r], P[mf][3][r]));
                v = fmaxf(v, __shfl_xor(v, 1));
                v = fmaxf(v, __shfl_xor(v, 2));
                v = fmaxf(v, __shfl_xor(v, 4));
                v = fmaxf(v, __shfl_xor(v, 8));
                pmax[mf][r] = v;
            }
        if (lr == 0) {
#pragma unroll
            for (int mf = 0; mf < 4; mf++)
                *(float4*)&wred[w][mf * 16 + g * 4] =
                    make_float4(pmax[mf][0], pmax[mf][1], pmax[mf][2], pmax[mf][3]);
        }
        __syncthreads();                       // B1
        if (w == 0) {
            float v = wred[0][lane];
#pragma unroll
            for (int ww = 1; ww < 8; ww++) v = fmaxf(v, wred[ww][lane]);
            tred[lane] = v;
        }
        __syncthreads();                       // B2

#pragma unroll
        for (int mf = 0; mf < 4; mf++) {
            float4 tm = *(const float4*)&tred[mf * 16 + g * 4];
            float tmr[4] = {tm.x, tm.y, tm.z, tm.w};
#pragma unroll
            for (int r = 0; r < 4; r++) {
                float mn = fmaxf(m_r[mf][r], tmr[r]);
                alpha[mf][r] = __expf(m_r[mf][r] - mn);
                m_r[mf][r] = mn;
            }
        }

        // ---- exp, mask, write Ps (bf16), partial sums ----
        float sE[4][4], sAp[4][4];
#pragma unroll
        for (int mf = 0; mf < 4; mf++)
#pragma unroll
            for (int r = 0; r < 4; r++) { sE[mf][r] = 0.f; sAp[mf][r] = 0.f; }

        const size_t mbase = ((size_t)b * SL + q0) * SL + kt * 512 + w * 64;
#pragma unroll
        for (int mf = 0; mf < 4; mf++)
#pragma unroll
            for (int nf = 0; nf < 4; nf++)
#pragma unroll
                for (int r = 0; r < 4; r++) {
                    int q = mf * 16 + g * 4 + r;
                    int k = w * 64 + nf * 16 + lr;
                    float e = __expf(P[mf][nf][r] - m_r[mf][r]);
                    float mk = mask[mbase + (size_t)q * SL + nf * 16 + lr];
                    float a = e * mk;
                    sE[mf][r] += e;
                    sAp[mf][r] += a;
                    int sb = q * 1024 + ((((k >> 3) ^ (q & 7)) << 4)) + ((k & 7) << 1);
                    *(unsigned short*)((char*)Ps + sb) = f2bf(a);
                }
#pragma unroll
        for (int mf = 0; mf < 4; mf++)
#pragma unroll
            for (int r = 0; r < 4; r++) {
                float e = sE[mf][r], a = sAp[mf][r];
                e += __shfl_xor(e, 1); e += __shfl_xor(e, 2);
                e += __shfl_xor(e, 4); e += __shfl_xor(e, 8);
                a += __shfl_xor(a, 1); a += __shfl_xor(a, 2);
                a += __shfl_xor(a, 4); a += __shfl_xor(a, 8);
                sE[mf][r] = e; sAp[mf][r] = a;
            }
        if (lr == 0) {
#pragma unroll
            for (int mf = 0; mf < 4; mf++) {
                *(float4*)&wred[w][mf * 16 + g * 4] =
                    make_float4(sE[mf][0], sE[mf][1], sE[mf][2], sE[mf][3]);
                *(float4*)&wredA[w][mf * 16 + g * 4] =
                    make_float4(sAp[mf][0], sAp[mf][1], sAp[mf][2], sAp[mf][3]);
            }
        }
        __syncthreads();                       // B3
        if (w == 0) {
            float e = wred[0][lane], a = wredA[0][lane];
#pragma unroll
            for (int ww = 1; ww < 8; ww++) { e += wred[ww][lane]; a += wredA[ww][lane]; }
            tred[lane] = e; tredA[lane] = a;
        }
        __syncthreads();                       // B4

#pragma unroll
        for (int mf = 0; mf < 4; mf++) {
            float4 te = *(const float4*)&tred[mf * 16 + g * 4];
            float4 ta = *(const float4*)&tredA[mf * 16 + g * 4];
            float ter[4] = {te.x, te.y, te.z, te.w};
            float tar[4] = {ta.x, ta.y, ta.z, ta.w};
#pragma unroll
            for (int r = 0; r < 4; r++) {
                l_r[mf][r]  = l_r[mf][r]  * alpha[mf][r] + ter[r];
                sA_r[mf][r] = sA_r[mf][r] * alpha[mf][r] + tar[r];
            }
        }
        // rescale O
#pragma unroll
        for (int mf = 0; mf < 4; mf++)
#pragma unroll
            for (int nh = 0; nh < 4; nh++)
#pragma unroll
                for (int r = 0; r < 4; r++) O[mf][nh][r] *= alpha[mf][r];

        // ---- PV: O[q][h-slice w*64..+64] += Ps * Vt ----
        const unsigned short* Vg = Vt + (size_t)(w * 64) * NS + b * SL + kt * 512;
#pragma unroll 2
        for (int ks = 0; ks < 512; ks += 32) {
            short8 pa[4], vb[4];
            int chb = (ks >> 3) + g;
#pragma unroll
            for (int mf = 0; mf < 4; mf++) {
                int q = mf * 16 + lr;
                pa[mf] = *(const short8*)((const char*)Ps + q * 1024 + ((chb ^ (q & 7)) << 4));
            }
#pragma unroll
            for (int nh = 0; nh < 4; nh++)
                vb[nh] = *(const short8*)(Vg + (size_t)(nh * 16 + lr) * NS + ks + g * 8);
#pragma unroll
            for (int mf = 0; mf < 4; mf++)
#pragma unroll
                for (int nh = 0; nh < 4; nh++)
                    O[mf][nh] = __builtin_amdgcn_mfma_f32_16x16x32_bf16(
                        pa[mf], vb[nh], O[mf][nh], 0, 0, 0);
        }
        // no barrier needed: next tile's Ps writes are fenced by B1/B2 above
    }

    // ---- epilogue: out = O / l ----
#pragma unroll
    for (int mf = 0; mf < 4; mf++)
#pragma unroll
        for (int r = 0; r < 4; r++) {
            float invl = 1.0f / l_r[mf][r];
            size_t rowoff = (size_t)(b * SL + q0 + mf * 16 + g * 4 + r) * HD;
#pragma unroll
            for (int nh = 0; nh < 4; nh++)
                out[rowoff + w * 64 + nh * 16 + lr] = O[mf][nh][r] * invl;
        }
    if (w == 0 && lr == 0) {
        float s = 0.f;
#pragma unroll
        for (int mf = 0; mf < 4; mf++)
#pragma unroll
            for (int r = 0; r < 4; r++) s += sA_r[mf][r] / l_r[mf][r];
        atomicAdd(&denom[b], s);
    }
}

__global__ void k_norm(float* __restrict__ out, const float* __restrict__ denom) {
    const int n4 = NB * SL * HD / 4;
    int i = blockIdx.x * blockDim.x + threadIdx.x;
    int stride = gridDim.x * blockDim.x;
    for (; i < n4; i += stride) {
        int b = i >> 17;  // (SL*HD/4) = 131072 per batch
        float inv = 1.0f / denom[b];
        float4 v = ((float4*)out)[i];
        v.x *= inv; v.y *= inv; v.z *= inv; v.w *= inv;
        ((float4*)out)[i] = v;
    }
}

extern "C" void kernel_launch(void* const* d_in, const int* in_sizes, int n_in,
                              void* d_out, int out_size, void* d_ws, size_t ws_size,
                              hipStream_t stream) {
    const float* x    = (const float*)d_in[0];
    const float* mask = (const float*)d_in[1];
    const float* Wq   = (const float*)d_in[2];
    const float* bq   = (const float*)d_in[3];
    const float* Wk   = (const float*)d_in[4];
    const float* bk   = (const float*)d_in[5];
    const float* Wv   = (const float*)d_in[6];
    const float* bv   = (const float*)d_in[7];
    float* out = (float*)d_out;

    const size_t SZ_X = (size_t)NS * HD * 2;   // 33.5 MB (bf16 tensor)
    const size_t SZ_W = (size_t)HD * HD * 2;

    size_t off = 0;
    char* base = (char*)d_ws;
    unsigned short* xb  = (unsigned short*)(base + off); off += SZ_X;
    unsigned short* Vt  = (unsigned short*)(base + off); off += SZ_X;
    unsigned short* Wqb = (unsigned short*)(base + off); off += SZ_W;
    unsigned short* Wkb = (unsigned short*)(base + off); off += SZ_W;
    unsigned short* Wvb = (unsigned short*)(base + off); off += SZ_W;
    float* den = (float*)(base + off); off += 256;

    unsigned short *Qm, *Km;
    if (ws_size >= off + 2 * SZ_X) {
        Qm = (unsigned short*)(base + off); off += SZ_X;
        Km = (unsigned short*)(base + off); off += SZ_X;
    } else {
        // fallback: x (fp32, 64MB) is dead after conversion to xb; harness
        // restores inputs before every launch, so it is safe scratch.
        Qm = (unsigned short*)d_in[0];
        Km = Qm + (size_t)NS * HD;
    }

    hipLaunchKernelGGL(k_zero, dim3(1), dim3(64), 0, stream, den, NB);
    hipLaunchKernelGGL(k_cvt, dim3(2048), dim3(256), 0, stream, x,  xb,  NS * HD / 8);
    hipLaunchKernelGGL(k_cvt, dim3(128),  dim3(256), 0, stream, Wq, Wqb, HD * HD / 8);
    hipLaunchKernelGGL(k_cvt, dim3(128),  dim3(256), 0, stream, Wk, Wkb, HD * HD / 8);
    hipLaunchKernelGGL(k_cvt, dim3(128),  dim3(256), 0, stream, Wv, Wvb, HD * HD / 8);

    // Q = xb * Wq^T + bq   -> [NS][HD]
    hipLaunchKernelGGL((k_gemm_bt<0>), dim3(HD / 128, NS / 128), dim3(256), 0, stream,
                       xb, Wqb, bq, Qm, NS, HD, HD);
    // K = xb * Wk^T + bk   -> [NS][HD]
    hipLaunchKernelGGL((k_gemm_bt<0>), dim3(HD / 128, NS / 128), dim3(256), 0, stream,
                       xb, Wkb, bk, Km, NS, HD, HD);
    // Vt = Wv * xb^T + bv  -> [HD][NS]  (so PV B-operand reads are contiguous)
    hipLaunchKernelGGL((k_gemm_bt<1>), dim3(NS / 128, HD / 128), dim3(256), 0, stream,
                       Wvb, xb, bv, Vt, HD, NS, HD);

    hipLaunchKernelGGL(k_flash, dim3(SL / 64, NB), dim3(512), 0, stream,
                       Qm, Km, Vt, mask, out, den);
    hipLaunchKernelGGL(k_norm, dim3(2048), dim3(256), 0, stream, out, den);
}

// Round 2
// 528.567 us; speedup vs baseline: 1.1928x; 1.1928x over previous
//
#include <hip/hip_runtime.h>
#include <stdint.h>

#define NB 32
#define SL 1024
#define HD 512
#define NS (NB * SL)   // 32768

typedef __attribute__((ext_vector_type(8))) short short8;   // 8 x bf16
typedef __attribute__((ext_vector_type(4))) short short4v;  // 4 x bf16
typedef __attribute__((ext_vector_type(4))) float f32x4;

__device__ __forceinline__ unsigned short f2bf(float f) {
    union { float f; uint32_t u; } c; c.f = f;
    uint32_t u = c.u;
    return (unsigned short)((u + 0x7FFFu + ((u >> 16) & 1u)) >> 16);
}

__device__ __forceinline__ void gl_lds16(const void* g, void* l) {
    __builtin_amdgcn_global_load_lds(
        (const __attribute__((address_space(1))) uint32_t*)g,
        (__attribute__((address_space(3))) uint32_t*)l, 16, 0, 0);
}

__device__ __forceinline__ f32x4 ntload4(const float* p) {
    return __builtin_nontemporal_load((const f32x4*)p);
}

// ---------------- convert x to bf16 ----------------
__global__ void k_cvt(const float* __restrict__ in, unsigned short* __restrict__ out, int n8) {
    int i = blockIdx.x * blockDim.x + threadIdx.x;
    int stride = gridDim.x * blockDim.x;
    for (; i < n8; i += stride) {
        const float4* p = (const float4*)in + (size_t)i * 2;
        float4 a = p[0], b = p[1];
        short8 v;
        v[0] = (short)f2bf(a.x); v[1] = (short)f2bf(a.y);
        v[2] = (short)f2bf(a.z); v[3] = (short)f2bf(a.w);
        v[4] = (short)f2bf(b.x); v[5] = (short)f2bf(b.y);
        v[6] = (short)f2bf(b.z); v[7] = (short)f2bf(b.w);
        *((short8*)out + i) = v;
    }
}

// ---------------- convert all 3 weights + zero denom (one launch) ----------------
__global__ void k_cvtw(const float* __restrict__ Wq, const float* __restrict__ Wk,
                       const float* __restrict__ Wv,
                       unsigned short* __restrict__ Wqk, unsigned short* __restrict__ Wvb,
                       float* __restrict__ den) {
    const int C8 = HD * HD / 8;   // 32768 chunks per weight
    int i = blockIdx.x * blockDim.x + threadIdx.x;   // grid covers 3*C8
    const float* src; unsigned short* dst; int j;
    if (i < C8)            { src = Wq; dst = Wqk;            j = i; }
    else if (i < 2 * C8)   { src = Wk; dst = Wqk + HD * HD;  j = i - C8; }
    else if (i < 3 * C8)   { src = Wv; dst = Wvb;            j = i - 2 * C8; }
    else return;
    const float4* p = (const float4*)src + (size_t)j * 2;
    float4 a = p[0], b = p[1];
    short8 v;
    v[0] = (short)f2bf(a.x); v[1] = (short)f2bf(a.y);
    v[2] = (short)f2bf(a.z); v[3] = (short)f2bf(a.w);
    v[4] = (short)f2bf(b.x); v[5] = (short)f2bf(b.y);
    v[6] = (short)f2bf(b.z); v[7] = (short)f2bf(b.w);
    *((short8*)dst + j) = v;
    if (i < NB) den[i] = 0.f;
}

// ---------------- bf16 GEMM: C[M][N] = A[M][K] * B[N][K]^T + bias ----------------
// BIAS_M==0: bias by col with split (col<nsplit -> bias, else bias2[col-nsplit]).
// BIAS_M==1: bias by row.
template<int BIAS_M>
__global__ __launch_bounds__(256, 4)
void k_gemm_bt(const unsigned short* __restrict__ A,
               const unsigned short* __restrict__ Bm,
               const float* __restrict__ bias,
               const float* __restrict__ bias2,
               int nsplit,
               unsigned short* __restrict__ C,
               int M, int N, int K) {
    __shared__ unsigned short As[128 * 64];
    __shared__ unsigned short Bs[128 * 64];
    const int t = threadIdx.x;
    const int lane = t & 63, w = t >> 6;
    const int wr = w >> 1, wc = w & 1;
    const int g = lane >> 4, lr = lane & 15;
    const int m0 = blockIdx.y * 128, n0 = blockIdx.x * 128;

    f32x4 acc[4][4];
#pragma unroll
    for (int i = 0; i < 4; i++)
#pragma unroll
        for (int j = 0; j < 4; j++) acc[i][j] = (f32x4){0.f, 0.f, 0.f, 0.f};

    for (int kt = 0; kt < K; kt += 64) {
#pragma unroll
        for (int i = 0; i < 4; i++) {
            int u = i * 256 + t;
            int row = u >> 3, c = u & 7;
            int sc = c ^ (row & 7);
            gl_lds16(A + (size_t)(m0 + row) * K + kt + sc * 8,
                     (char*)As + (size_t)(i * 256 + w * 64) * 16);
        }
#pragma unroll
        for (int i = 0; i < 4; i++) {
            int u = i * 256 + t;
            int row = u >> 3, c = u & 7;
            int sc = c ^ (row & 7);
            gl_lds16(Bm + (size_t)(n0 + row) * K + kt + sc * 8,
                     (char*)Bs + (size_t)(i * 256 + w * 64) * 16);
        }
        __syncthreads();
#pragma unroll
        for (int ks = 0; ks < 2; ks++) {
            short8 af[4], bf[4];
#pragma unroll
            for (int mf = 0; mf < 4; mf++) {
                int row = wr * 64 + mf * 16 + lr;
                int ch = (ks * 4 + g) ^ (row & 7);
                af[mf] = *(const short8*)((const char*)As + row * 128 + ch * 16);
            }
#pragma unroll
            for (int nf = 0; nf < 4; nf++) {
                int row = wc * 64 + nf * 16 + lr;
                int ch = (ks * 4 + g) ^ (row & 7);
                bf[nf] = *(const short8*)((const char*)Bs + row * 128 + ch * 16);
            }
#pragma unroll
            for (int mf = 0; mf < 4; mf++)
#pragma unroll
                for (int nf = 0; nf < 4; nf++)
                    acc[mf][nf] = __builtin_amdgcn_mfma_f32_16x16x32_bf16(
                        af[mf], bf[nf], acc[mf][nf], 0, 0, 0);
        }
        __syncthreads();
    }
#pragma unroll
    for (int mf = 0; mf < 4; mf++) {
#pragma unroll
        for (int nf = 0; nf < 4; nf++) {
            int col = n0 + wc * 64 + nf * 16 + lr;
            int row0 = m0 + wr * 64 + mf * 16 + g * 4;
            float cb = 0.f;
            if (!BIAS_M) cb = (col < nsplit) ? bias[col] : bias2[col - nsplit];
#pragma unroll
            for (int r = 0; r < 4; r++) {
                float v = acc[mf][nf][r] + (BIAS_M ? bias[row0 + r] : cb);
                C[(size_t)(row0 + r) * N + col] = f2bf(v);
            }
        }
    }
}

// ---------------- fused attention (no-max softmax, swapped QK^T) ----------------
// Block: 1024 threads = 16 waves; 64 q-rows; K in 2 tiles of 512.
// Wave w: k-slice [w*32, w*32+32) for QK^T; h-slice [w*32, w*32+32) for PV.
__global__ __launch_bounds__(1024, 4)
void k_flash(const unsigned short* __restrict__ QK,  // [NS][1024]: cols 0..511 Q, 512..1023 K
             const unsigned short* __restrict__ Vt,  // [HD][NS]
             const float* __restrict__ mask,         // [NB][SL][SL]
             float* __restrict__ out,                // [NB][SL][HD]
             float* __restrict__ denom) {            // [NB]
    __shared__ unsigned short Qs[64 * 512];   // swizzled 16B chunks
    __shared__ unsigned short Ps[64 * 512];
    __shared__ float wredL[16 * 64];
    __shared__ float wredA[16 * 64];
    __shared__ float tredL[64];
    __shared__ float tredA[64];

    const int t = threadIdx.x;
    const int lane = t & 63, w = t >> 6;
    const int g = lane >> 4, lr = lane & 15;
    // XCD swizzle: 512 blocks, 8 XCDs -> 64 contiguous (4 batches) per XCD
    const int bid = blockIdx.x;
    const int nid = (bid & 7) * 64 + (bid >> 3);
    const int b = nid >> 4, qt = nid & 15;
    const int q0 = qt * 64;

    // stage Q tile 64x512 bf16 (chunk-swizzled)
    const unsigned short* Qg = QK + (size_t)(b * SL + q0) * 1024;
#pragma unroll
    for (int i = 0; i < 4; i++) {
        int u = i * 1024 + t;
        int row = u >> 6, c = u & 63;
        int sc = c ^ (row & 7);
        gl_lds16(Qg + (size_t)row * 1024 + sc * 8,
                 (char*)Qs + (size_t)(i * 1024 + w * 64) * 16);
    }

    f32x4 O[4][2];
    float lsum[4], asum[4];
#pragma unroll
    for (int qf = 0; qf < 4; qf++) {
        lsum[qf] = 0.f; asum[qf] = 0.f;
        O[qf][0] = (f32x4){0.f, 0.f, 0.f, 0.f};
        O[qf][1] = (f32x4){0.f, 0.f, 0.f, 0.f};
    }
    __syncthreads();   // Q staged

    const float iscale = 0.04419417382415922f;  // 1/sqrt(512)

    for (int kt = 0; kt < 2; kt++) {
        // ---- QK^T (swapped): P^T[k 32][q 64] per wave ----
        f32x4 P[2][4];   // [kf][qf]
#pragma unroll
        for (int kf = 0; kf < 2; kf++)
#pragma unroll
            for (int qf = 0; qf < 4; qf++) P[kf][qf] = (f32x4){0.f, 0.f, 0.f, 0.f};

        const unsigned short* Kg = QK + 512 + (size_t)(b * SL + kt * 512 + w * 32) * 1024;
#pragma unroll 4
        for (int h = 0; h < HD; h += 32) {
            short8 ka[2], qb[4];
#pragma unroll
            for (int kf = 0; kf < 2; kf++)
                ka[kf] = *(const short8*)(Kg + (size_t)(kf * 16 + lr) * 1024 + h + g * 8);
#pragma unroll
            for (int qf = 0; qf < 4; qf++) {
                int q = qf * 16 + lr;
                int sc = ((h >> 3) + g) ^ (q & 7);
                qb[qf] = *(const short8*)((const char*)Qs + q * 1024 + sc * 16);
            }
#pragma unroll
            for (int kf = 0; kf < 2; kf++)
#pragma unroll
                for (int qf = 0; qf < 4; qf++)
                    P[kf][qf] = __builtin_amdgcn_mfma_f32_16x16x32_bf16(
                        ka[kf], qb[qf], P[kf][qf], 0, 0, 0);
        }

        if (kt) __syncthreads();   // all waves done reading Ps (prev tile PV)

        // ---- mask loads (vector, nontemporal), exp, A=e*mk, Ps write ----
        const float* mrow = mask + ((size_t)(b * SL + q0)) * SL + kt * 512 + w * 32;
        f32x4 mv[4][2];
#pragma unroll
        for (int qf = 0; qf < 4; qf++)
#pragma unroll
            for (int kf = 0; kf < 2; kf++)
                mv[qf][kf] = ntload4(mrow + (size_t)(qf * 16 + lr) * SL + kf * 16 + g * 4);

#pragma unroll
        for (int qf = 0; qf < 4; qf++) {
            int q = qf * 16 + lr;
#pragma unroll
            for (int kf = 0; kf < 2; kf++) {
                f32x4 e;
#pragma unroll
                for (int r = 0; r < 4; r++) e[r] = __expf(P[kf][qf][r] * iscale);
                lsum[qf] += e[0] + e[1] + e[2] + e[3];
                f32x4 a = e * mv[qf][kf];
                asum[qf] += a[0] + a[1] + a[2] + a[3];
                short4v pk;
                pk[0] = (short)f2bf(a[0]); pk[1] = (short)f2bf(a[1]);
                pk[2] = (short)f2bf(a[2]); pk[3] = (short)f2bf(a[3]);
                int chunk = w * 4 + kf * 2 + (g >> 1);
                int sc = chunk ^ (q & 7);
                *(short4v*)((char*)Ps + q * 1024 + sc * 16 + (g & 1) * 8) = pk;
            }
        }
        __syncthreads();   // Ps ready

        // ---- PV: O[q 64][h 32-per-wave] += P * Vt ----
        const unsigned short* Vg = Vt + (size_t)(w * 32) * NS + (size_t)b * SL + kt * 512;
#pragma unroll 4
        for (int ks = 0; ks < 512; ks += 32) {
            short8 pa[4], vb[2];
#pragma unroll
            for (int qf = 0; qf < 4; qf++) {
                int q = qf * 16 + lr;
                int sc = ((ks >> 3) + g) ^ (q & 7);
                pa[qf] = *(const short8*)((const char*)Ps + q * 1024 + sc * 16);
            }
#pragma unroll
            for (int nh = 0; nh < 2; nh++)
                vb[nh] = *(const short8*)(Vg + (size_t)(nh * 16 + lr) * NS + ks + g * 8);
#pragma unroll
            for (int qf = 0; qf < 4; qf++)
#pragma unroll
                for (int nh = 0; nh < 2; nh++)
                    O[qf][nh] = __builtin_amdgcn_mfma_f32_16x16x32_bf16(
                        pa[qf], vb[nh], O[qf][nh], 0, 0, 0);
        }
    }

    // ---- deferred row-sum reduction (once) ----
#pragma unroll
    for (int qf = 0; qf < 4; qf++) {
        float L = lsum[qf], A = asum[qf];
        L += __shfl_xor(L, 16); L += __shfl_xor(L, 32);
        A += __shfl_xor(A, 16); A += __shfl_xor(A, 32);
        if (g == 0) {
            wredL[w * 64 + qf * 16 + lr] = L;
            wredA[w * 64 + qf * 16 + lr] = A;
        }
    }
    __syncthreads();
    if (t < 64) {
        float L = 0.f, A = 0.f;
#pragma unroll
        for (int ww = 0; ww < 16; ww++) { L += wredL[ww * 64 + t]; A += wredA[ww * 64 + t]; }
        tredL[t] = L; tredA[t] = A;
    }
    __syncthreads();

    // ---- epilogue: out = O / l ----
#pragma unroll
    for (int qf = 0; qf < 4; qf++) {
        f32x4 Lv = *(const f32x4*)&tredL[qf * 16 + g * 4];
#pragma unroll
        for (int r = 0; r < 4; r++) {
            float invl = 1.0f / Lv[r];
            size_t rowoff = (size_t)(b * SL + q0 + qf * 16 + g * 4 + r) * HD;
#pragma unroll
            for (int nh = 0; nh < 2; nh++)
                out[rowoff + w * 32 + nh * 16 + lr] = O[qf][nh][r] * invl;
        }
    }
    if (t < 64) {
        float d = tredA[t] / tredL[t];
        d += __shfl_xor(d, 1); d += __shfl_xor(d, 2); d += __shfl_xor(d, 4);
        d += __shfl_xor(d, 8); d += __shfl_xor(d, 16); d += __shfl_xor(d, 32);
        if (lane == 0) atomicAdd(&denom[b], d);
    }
}

__global__ void k_norm(float* __restrict__ out, const float* __restrict__ denom) {
    const int n4 = NB * SL * HD / 4;
    int i = blockIdx.x * blockDim.x + threadIdx.x;
    int stride = gridDim.x * blockDim.x;
    for (; i < n4; i += stride) {
        int b = i >> 17;
        float inv = 1.0f / denom[b];
        float4 v = ((float4*)out)[i];
        v.x *= inv; v.y *= inv; v.z *= inv; v.w *= inv;
        ((float4*)out)[i] = v;
    }
}

extern "C" void kernel_launch(void* const* d_in, const int* in_sizes, int n_in,
                              void* d_out, int out_size, void* d_ws, size_t ws_size,
                              hipStream_t stream) {
    const float* x    = (const float*)d_in[0];
    const float* mask = (const float*)d_in[1];
    const float* Wq   = (const float*)d_in[2];
    const float* bq   = (const float*)d_in[3];
    const float* Wk   = (const float*)d_in[4];
    const float* bk   = (const float*)d_in[5];
    const float* Wv   = (const float*)d_in[6];
    const float* bv   = (const float*)d_in[7];
    float* out = (float*)d_out;

    const size_t SZ_X = (size_t)NS * HD * 2;   // 33.55 MB
    const size_t SZ_W = (size_t)HD * HD * 2;

    // total = 4*SZ_X + 3*SZ_W + 256 = 135,790,848 B (== round-1-proven ws requirement)
    size_t off = 0;
    char* base = (char*)d_ws;
    unsigned short* xb  = (unsigned short*)(base + off); off += SZ_X;
    unsigned short* Vt  = (unsigned short*)(base + off); off += SZ_X;
    unsigned short* QKm = (unsigned short*)(base + off); off += 2 * SZ_X;  // [NS][1024]
    unsigned short* Wqk = (unsigned short*)(base + off); off += 2 * SZ_W;  // [1024][512]
    unsigned short* Wvb = (unsigned short*)(base + off); off += SZ_W;
    float* den = (float*)(base + off); off += 256;

    hipLaunchKernelGGL(k_cvt, dim3(2048), dim3(256), 0, stream, x, xb, NS * HD / 8);
    hipLaunchKernelGGL(k_cvtw, dim3(384), dim3(256), 0, stream, Wq, Wk, Wv, Wqk, Wvb, den);

    // [Q|K] = xb * Wqk^T + [bq|bk]  -> [NS][1024]
    hipLaunchKernelGGL((k_gemm_bt<0>), dim3(1024 / 128, NS / 128), dim3(256), 0, stream,
                       xb, Wqk, bq, bk, HD, QKm, NS, 1024, HD);
    // Vt = Wv * xb^T + bv  -> [HD][NS]
    hipLaunchKernelGGL((k_gemm_bt<1>), dim3(NS / 128, HD / 128), dim3(256), 0, stream,
                       Wvb, xb, bv, bv, 1 << 30, Vt, HD, NS, HD);

    hipLaunchKernelGGL(k_flash, dim3(512), dim3(1024), 0, stream,
                       QKm, Vt, mask, out, den);
    hipLaunchKernelGGL(k_norm, dim3(2048), dim3(256), 0, stream, out, den);
}